// Round 6
// baseline (61.352 us; speedup 1.0000x reference)
//
#include <hip/hip_runtime.h>
#include <math.h>

// ThermostatNN: B independent 40-step rollouts of a 2->64->1 MLP plant +
// hysteresis thermostat. One thread per batch element.
//
// R6 change vs R5 (theory: LICM hoisted the loop-invariant LDS weight reads
// back into registers -> 128 uniform floats -> AGPR parking -> +192
// v_accvgpr_read per step; measured ~440 VALU insts/step, VALUBusy 103%,
// occupancy capped at 2 waves/SIMD by the unified VGPR+AGPR budget):
//  - The weight reads are now addressed via `woff`, an offset made opaque by
//    asm volatile("" : "+v"(woff)) INSIDE the t-loop. Every load depends on
//    a value the compiler must assume changes per iteration, so the 16
//    ds_read_b128 stay in the loop (one vaddr, immediate offsets). All lanes
//    read the same address -> LDS broadcast, conflict-free, issued on the
//    lgkm pipe and hidden under ~450 VALU cycles/step.
//  - No register-resident weights -> no AGPRs -> ~110 VGPRs ->
//    4 waves/SIMD resident (grid supplies exactly 16 waves/CU).
//
// NUMERICS (do not touch): serial single-accumulator dot in j order, expf-
// based stable sigmoid, explicitly rounded updates. absmax == 0.0 in R1-R5;
// op order and rounding must stay bit-identical. No reassociation: a ~1e-7
// perturbation can flip hysteresis decisions (10.5M of them) and one flip
// diverges a trajectory by O(100).

#define LHID 64
#define NSTEPS 40

__global__ __launch_bounds__(256, 2) void thermostat_kernel(
    const float* __restrict__ x_init,  // (B,4): step, isOn, temp, aux
    const float* __restrict__ W1,      // (2,64) row-major
    const float* __restrict__ b1,      // (64)
    const float* __restrict__ W2,      // (64,1)
    const float* __restrict__ b2,      // (1)
    float* __restrict__ out,           // (40,B)
    int B)
{
    // [0:64) = W1 row 0, [64:128) = W2
    __shared__ __align__(16) float lds_w[2 * LHID];

    int tid = threadIdx.x;
    if (tid < LHID) {
        lds_w[tid]        = W1[tid];
        lds_w[LHID + tid] = W2[tid];
    }
    __syncthreads();

    int b = blockIdx.x * blockDim.x + tid;
    if (b >= B) return;

    float4 st = reinterpret_cast<const float4*>(x_init)[b];
    float step0 = st.x;
    float isOn  = st.y;
    float temp  = st.z;
    float aux   = st.w;
    float bias2 = b2[0];

    // number of active iterations: #t with step0 + t < NSTEPS
    int n_active = (int)ceilf(fminf(fmaxf((float)NSTEPS - step0, 0.0f), (float)NSTEPS));

    // Per-thread invariant part of layer 1: c[j] = aux*W1[1][j] + b1[j].
    // Pinned opaque so the allocator cannot rematerialize (R2/R3 lesson).
    float c[LHID];
#pragma unroll
    for (int j = 0; j < LHID; j += 4) {
        float4 vr1 = *reinterpret_cast<const float4*>(&W1[LHID + j]);
        float4 vb  = *reinterpret_cast<const float4*>(&b1[j]);
        c[j+0] = fmaf(aux, vr1.x, vb.x);
        c[j+1] = fmaf(aux, vr1.y, vb.y);
        c[j+2] = fmaf(aux, vr1.z, vb.z);
        c[j+3] = fmaf(aux, vr1.w, vb.w);
    }
#pragma unroll
    for (int j = 0; j < LHID; ++j) {
        asm volatile("" : "+v"(c[j]));
    }

    float* po = out + b;
    unsigned woff = 0;  // opaque LDS byte-offset; breaks LICM of the weight reads

#pragma unroll 1
    for (int t = 0; t < NSTEPS; ++t) {
        asm volatile("" : "+v"(woff));  // redefine per-iteration: loads can't hoist
        const float4* pw = reinterpret_cast<const float4*>(
            reinterpret_cast<const char*>(lds_w) + woff);

        // ---- plant NN: s = sigmoid(relu([temp,aux]@W1 + b1) @ W2 + b2) ----
        float acc = 0.0f;
#pragma unroll
        for (int j = 0; j < LHID; j += 4) {
            float4 av = pw[j / 4];        // ds_read_b128 (broadcast)
            float4 wv = pw[16 + j / 4];   // ds_read_b128 (broadcast)
            float h0 = fmaxf(fmaf(temp, av.x, c[j+0]), 0.0f); acc = fmaf(h0, wv.x, acc);
            float h1 = fmaxf(fmaf(temp, av.y, c[j+1]), 0.0f); acc = fmaf(h1, wv.y, acc);
            float h2 = fmaxf(fmaf(temp, av.z, c[j+2]), 0.0f); acc = fmaf(h2, wv.z, acc);
            float h3 = fmaxf(fmaf(temp, av.w, c[j+3]), 0.0f); acc = fmaf(h3, wv.w, acc);
        }
        float x = __fadd_rn(acc, bias2);

        // stable sigmoid, single exact division (bitwise == two-branch form)
        float e = expf(-fabsf(x));
        float num = (x >= 0.0f) ? 1.0f : e;
        float s = num / (1.0f + e);

        // plant = s*10 - 5 ; dtemp = plant*10
        float plant = __fsub_rn(__fmul_rn(s, 10.0f), 5.0f);
        float dtemp = __fmul_rn(plant, 10.0f);

        float tn_off = __fadd_rn(temp, dtemp);
        float tn_on  = __fadd_rn(tn_off, 5.0f);

        bool off = (isOn <= 0.5f);
        float temp_new = off ? tn_off : tn_on;
        float isOn_new;
        if (off) isOn_new = (temp_new <= 66.0f) ? 1.0f : isOn;
        else     isOn_new = (temp_new <= 78.0f) ? isOn : 0.0f;

        if (t < n_active) {
            temp = temp_new;
            isOn = isOn_new;
        }

        *po = temp;
        po += B;
    }
}

extern "C" void kernel_launch(void* const* d_in, const int* in_sizes, int n_in,
                              void* d_out, int out_size, void* d_ws, size_t ws_size,
                              hipStream_t stream) {
    const float* x_init = (const float*)d_in[0];
    const float* W1     = (const float*)d_in[1];
    const float* b1     = (const float*)d_in[2];
    const float* W2     = (const float*)d_in[3];
    const float* b2     = (const float*)d_in[4];
    float* out = (float*)d_out;

    int B = in_sizes[0] / 4;
    int threads = 256;
    int blocks = (B + threads - 1) / threads;
    thermostat_kernel<<<blocks, threads, 0, stream>>>(x_init, W1, b1, W2, b2, out, B);
}